// Round 1
// baseline (130.963 us; speedup 1.0000x reference)
//
#include <hip/hip_runtime.h>
#include <math.h>

#define SDIM 512
#define DDIM 256
#define NBATCH 4
#define SSQ (SDIM*SDIM)            // 262144
#define MED_K ((SSQ-1)/2)          // 131071
#define NBINS 4096

// ---- workspace layout (bytes) ----
#define OFF_DISTS   0ull                               // 4 MB: float[4][512][512]
#define OFF_HIST    (4ull<<20)                         // 64 KB: uint[4][4096]
#define OFF_STATS   ((4ull<<20) + 65536ull)            // 128 B: per batch 4 doubles: sum, sumsq, (maxbits|conn)
#define OFF_MED     ((4ull<<20) + 65536ull + 128ull)   // 64 B: per batch 4 uint: -,-,thr_bits,ncomp
#define OFF_SIGNAL  ((4ull<<20) + 69632ull)            // 4 KB: float[4][256]
#define OFF_ADJ     ((4ull<<20) + 73728ull)            // 128 KB: u64[4][512][8]

// ---------------------------------------------------------------------------
// 1) pairwise distances, 64x64 tile per block, 4x4 pairs per thread.
//    also block-reduces global max distance (atomicMax on float bits).
__global__ __launch_bounds__(256) void k_dist(const float* __restrict__ x,
                                              float* __restrict__ dists,
                                              double* __restrict__ stats) {
    const int b  = blockIdx.z;
    const int i0 = blockIdx.y * 64, j0 = blockIdx.x * 64;
    __shared__ float As[64][68];
    __shared__ float Bs[64][68];
    const int tid = threadIdx.x;
    const int tx = tid & 15, ty = tid >> 4;
    float acc[4][4] = {};
    const float* xb = x + (size_t)b * SDIM * DDIM;

    for (int kc = 0; kc < 4; ++kc) {
        const int k0 = kc * 64;
#pragma unroll
        for (int rr = 0; rr < 4; ++rr) {
            int r = ty + rr * 16;
            float4 a4 = *(const float4*)(xb + (size_t)(i0 + r) * DDIM + k0 + tx * 4);
            float4 b4 = *(const float4*)(xb + (size_t)(j0 + r) * DDIM + k0 + tx * 4);
            *(float4*)&As[r][tx * 4] = a4;
            *(float4*)&Bs[r][tx * 4] = b4;
        }
        __syncthreads();
#pragma unroll
        for (int kk = 0; kk < 16; ++kk) {
            float4 av[4], bv[4];
#pragma unroll
            for (int a = 0; a < 4; ++a) av[a] = *(const float4*)&As[ty * 4 + a][kk * 4];
#pragma unroll
            for (int c = 0; c < 4; ++c) bv[c] = *(const float4*)&Bs[tx + 16 * c][kk * 4];
#pragma unroll
            for (int a = 0; a < 4; ++a)
#pragma unroll
                for (int c = 0; c < 4; ++c) {
                    float d0 = av[a].x - bv[c].x;
                    float d1 = av[a].y - bv[c].y;
                    float d2 = av[a].z - bv[c].z;
                    float d3 = av[a].w - bv[c].w;
                    acc[a][c] = fmaf(d0, d0, acc[a][c]);
                    acc[a][c] = fmaf(d1, d1, acc[a][c]);
                    acc[a][c] = fmaf(d2, d2, acc[a][c]);
                    acc[a][c] = fmaf(d3, d3, acc[a][c]);
                }
        }
        __syncthreads();
    }

    float* db = dists + (size_t)b * SSQ;
    float bm = 0.f;
#pragma unroll
    for (int a = 0; a < 4; ++a) {
        int i = i0 + ty * 4 + a;
#pragma unroll
        for (int c = 0; c < 4; ++c) {
            float sq = acc[a][c];
            float d  = sq > 0.f ? sqrtf(sq) : 0.f;
            bm = fmaxf(bm, d);
            db[(size_t)i * SDIM + j0 + tx + 16 * c] = d;
        }
    }
    // block max -> global atomicMax on float bits (all dists >= 0)
#pragma unroll
    for (int off = 32; off; off >>= 1) bm = fmaxf(bm, __shfl_xor(bm, off));
    __shared__ float wm[4];
    if ((tid & 63) == 0) wm[tid >> 6] = bm;
    __syncthreads();
    if (tid == 0) {
        float m = fmaxf(fmaxf(wm[0], wm[1]), fmaxf(wm[2], wm[3]));
        atomicMax((unsigned*)(stats + (size_t)b * 4 + 2), __float_as_uint(m));
    }
}

// ---------------------------------------------------------------------------
// 2) linear-bin histogram over [0, maxd], LDS-privatized.
__global__ __launch_bounds__(256) void k_hist(const float* __restrict__ dists,
                                              const double* __restrict__ stats,
                                              unsigned* __restrict__ ghist) {
    const int b = blockIdx.y;
    __shared__ unsigned lh[NBINS];
    const int tid = threadIdx.x;
    for (int t = tid; t < NBINS; t += 256) lh[t] = 0;
    __syncthreads();
    const float maxd = __uint_as_float(((const unsigned*)(stats + (size_t)b * 4 + 2))[0]);
    const float scale = (float)NBINS / maxd;
    const float* db = dists + (size_t)b * SSQ + (size_t)blockIdx.x * 4096;
#pragma unroll 4
    for (int t = 0; t < 16; ++t) {
        float d = db[t * 256 + tid];
        int bin = (int)(d * scale);
        bin = bin > (NBINS - 1) ? (NBINS - 1) : bin;
        atomicAdd(&lh[bin], 1u);
    }
    __syncthreads();
    unsigned* gh = ghist + (size_t)b * NBINS;
    for (int t = tid; t < NBINS; t += 256) if (lh[t]) atomicAdd(&gh[t], lh[t]);
}

// ---------------------------------------------------------------------------
// 3) select median bin -> thr (bin midpoint; error <= maxd/8192, harmless)
__global__ __launch_bounds__(256) void k_sel(const unsigned* __restrict__ ghist,
                                             const double* __restrict__ stats,
                                             unsigned* __restrict__ med) {
    const int b = blockIdx.x, tid = threadIdx.x;
    const unsigned* h = ghist + (size_t)b * NBINS;
    unsigned local = 0;
    for (int t = 0; t < 16; ++t) local += h[tid * 16 + t];
    __shared__ unsigned psum[256];
    psum[tid] = local;
    __syncthreads();
    for (int off = 1; off < 256; off <<= 1) {
        unsigned v = 0;
        if (tid >= off) v = psum[tid - off];
        __syncthreads();
        psum[tid] += v;
        __syncthreads();
    }
    const unsigned excl = psum[tid] - local;
    const unsigned k = MED_K;
    if (k >= excl && k < excl + local) {
        unsigned run = excl;
        int bucket = tid * 16;
        for (int t = 0; t < 16; ++t) {
            unsigned c = h[tid * 16 + t];
            if (k < run + c) { bucket = tid * 16 + t; break; }
            run += c;
        }
        const float maxd = __uint_as_float(((const unsigned*)(stats + (size_t)b * 4 + 2))[0]);
        const float thr = ((float)bucket + 0.5f) * (maxd / (float)NBINS);
        med[b * 4 + 2] = __float_as_uint(thr);
    }
}

// ---------------------------------------------------------------------------
// 4) adjacency bitmask build (ballot) + triu stats + edge count
__global__ __launch_bounds__(256) void k_adjstats(const float* __restrict__ dists,
                                                  const unsigned* __restrict__ med,
                                                  unsigned long long* __restrict__ adj,
                                                  double* __restrict__ stats) {
    const int b = blockIdx.y;
    const float thr = __uint_as_float(med[b * 4 + 2]);
    const int w = threadIdx.x >> 6, lane = threadIdx.x & 63;
    const int i = blockIdx.x * 4 + w;
    const float* row = dists + (size_t)b * SSQ + (size_t)i * SDIM;
    float fsum = 0.f, fsumsq = 0.f, fmaxv = 0.f;
    int conn = 0;
    unsigned long long words[8];
#pragma unroll
    for (int c = 0; c < 8; ++c) {
        int j = c * 64 + lane;
        float d = row[j];
        bool pred = (d < thr) && (j != i);
        words[c] = __ballot(pred ? 1 : 0);
        conn += pred ? 1 : 0;
        if (j >= i) { fsum += d; fsumsq += d * d; }
        fmaxv = fmaxf(fmaxv, d);
    }
    if (lane == 0) {
#pragma unroll
        for (int c = 0; c < 8; ++c) adj[((size_t)b * SDIM + i) * 8 + c] = words[c];
    }
    double s = (double)fsum, q = (double)fsumsq;
#pragma unroll
    for (int off = 32; off; off >>= 1) {
        s += __shfl_xor(s, off);
        q += __shfl_xor(q, off);
        fmaxv = fmaxf(fmaxv, __shfl_xor(fmaxv, off));
        conn += __shfl_xor(conn, off);
    }
    __shared__ double sh_s[4], sh_q[4];
    __shared__ float sh_m[4];
    __shared__ int sh_c[4];
    if (lane == 0) { sh_s[w] = s; sh_q[w] = q; sh_m[w] = fmaxv; sh_c[w] = conn; }
    __syncthreads();
    if (threadIdx.x == 0) {
        double S0 = sh_s[0] + sh_s[1] + sh_s[2] + sh_s[3];
        double Q0 = sh_q[0] + sh_q[1] + sh_q[2] + sh_q[3];
        float  M0 = fmaxf(fmaxf(sh_m[0], sh_m[1]), fmaxf(sh_m[2], sh_m[3]));
        unsigned C0 = (unsigned)(sh_c[0] + sh_c[1] + sh_c[2] + sh_c[3]);
        double* st = stats + (size_t)b * 4;
        atomicAdd(&st[0], S0);
        atomicAdd(&st[1], Q0);
        atomicMax((unsigned*)&st[2], __float_as_uint(M0));
        atomicAdd(((unsigned*)&st[2]) + 1, C0);
    }
}

// ---------------------------------------------------------------------------
// 5) connected components: whole graph in LDS, sync min-label propagation to
//    convergence (reference while_loop semantics). One block per batch.
__global__ __launch_bounds__(1024) void k_cc(const unsigned long long* __restrict__ adj,
                                             unsigned* __restrict__ med) {
    const int b = blockIdx.x;
    __shared__ unsigned long long am[SDIM * 8];   // 32 KB
    __shared__ int lab[SDIM], nlab[SDIM];
    __shared__ int changed, cnt;
    const int tid = threadIdx.x;
    const unsigned long long* ab = adj + (size_t)b * SDIM * 8;
    for (int t = tid; t < SDIM * 8; t += 1024) am[t] = ab[t];
    if (tid < SDIM) lab[tid] = tid;
    __syncthreads();

    for (int iter = 0; iter < 1024; ++iter) {
        if (tid < SDIM) nlab[tid] = lab[tid];
        if (tid == 0) changed = 0;
        __syncthreads();
        const int i = tid >> 1;
        const int wbase = (tid & 1) * 4;
        int mn = 0x7fffffff;
#pragma unroll
        for (int c = 0; c < 4; ++c) {
            unsigned long long wv = am[i * 8 + wbase + c];
            const int jb = (wbase + c) * 64;
            while (wv) {
                int j = __builtin_ctzll(wv);
                wv &= wv - 1;
                mn = min(mn, lab[jb + j]);
            }
        }
        atomicMin(&nlab[i], mn);
        __syncthreads();
        if (tid < SDIM) {
            if (nlab[tid] != lab[tid]) { lab[tid] = nlab[tid]; changed = 1; }
        }
        __syncthreads();
        if (!changed) break;
    }

    if (tid == 0) cnt = 0;
    __syncthreads();
    if (tid < SDIM && lab[tid] == tid) atomicAdd(&cnt, 1);
    __syncthreads();
    if (tid == 0) med[b * 4 + 3] = (unsigned)cnt;
}

// ---------------------------------------------------------------------------
// 6) topo features -> signal = topo @ W^T + bias
__global__ __launch_bounds__(256) void k_signal(const double* __restrict__ stats,
                                                const unsigned* __restrict__ med,
                                                const float* __restrict__ W,
                                                const float* __restrict__ bias,
                                                float* __restrict__ signal) {
    const int b = blockIdx.x, d = threadIdx.x;
    const double* st = stats + (size_t)b * 4;
    const double sum = st[0], sumsq = st[1];
    const unsigned maxbits = ((const unsigned*)&st[2])[0];
    const unsigned conn    = ((const unsigned*)&st[2])[1];
    const unsigned ncomp   = med[b * 4 + 3];
    const double cntf = (double)(SDIM * (SDIM + 1) / 2);
    const double mean = sum / cntf;
    double var = (sumsq - sum * sum / cntf) / (cntf - 1.0);
    var = var > 0.0 ? var : 0.0;
    const float t0 = (float)((double)conn / (double)(SDIM * (SDIM - 1)));
    const float t1 = (float)ncomp / (float)SDIM;
    const float t2 = (float)((double)conn / (double)(SDIM * SDIM));
    const float t3 = (float)mean;
    const float t4 = (float)sqrt(var);
    const float t6 = __uint_as_float(maxbits);
    const float* w = W + d * 8;
    float sig = bias[d] + t0 * w[0] + t1 * w[1] + t2 * w[2] + t3 * w[3] + t4 * w[4] + t6 * w[6];
    signal[b * DDIM + d] = sig;
}

// ---------------------------------------------------------------------------
// 7) residual + LayerNorm, wave per row (D=256 -> 4 floats/lane)
__global__ __launch_bounds__(256) void k_ln(const float* __restrict__ x,
                                            const float* __restrict__ signal,
                                            const float* __restrict__ gamma,
                                            const float* __restrict__ beta,
                                            float* __restrict__ out) {
    const int tid = threadIdx.x;
    const int w = tid >> 6, lane = tid & 63;
    const int row = blockIdx.x * 4 + w;          // 0..2047
    const int b = row >> 9;
    const float4 xv = *(const float4*)(x + (size_t)row * DDIM + lane * 4);
    const float4 sg = *(const float4*)(signal + (size_t)b * DDIM + lane * 4);
    float h0 = xv.x + sg.x, h1 = xv.y + sg.y, h2 = xv.z + sg.z, h3 = xv.w + sg.w;
    float s = h0 + h1 + h2 + h3;
#pragma unroll
    for (int off = 32; off; off >>= 1) s += __shfl_xor(s, off);
    const float mu = s * (1.0f / 256.0f);
    const float d0 = h0 - mu, d1 = h1 - mu, d2 = h2 - mu, d3 = h3 - mu;
    float q = d0 * d0 + d1 * d1 + d2 * d2 + d3 * d3;
#pragma unroll
    for (int off = 32; off; off >>= 1) q += __shfl_xor(q, off);
    const float var = q * (1.0f / 256.0f);
    const float r = 1.0f / sqrtf(var + 1e-5f);
    const float4 g  = *(const float4*)(gamma + lane * 4);
    const float4 be = *(const float4*)(beta + lane * 4);
    float4 o;
    o.x = d0 * r * g.x + be.x;
    o.y = d1 * r * g.y + be.y;
    o.z = d2 * r * g.z + be.z;
    o.w = d3 * r * g.w + be.w;
    *(float4*)(out + (size_t)row * DDIM + lane * 4) = o;
}

// ---------------------------------------------------------------------------
extern "C" void kernel_launch(void* const* d_in, const int* in_sizes, int n_in,
                              void* d_out, int out_size, void* d_ws, size_t ws_size,
                              hipStream_t stream) {
    (void)in_sizes; (void)n_in; (void)out_size; (void)ws_size;
    const float* x     = (const float*)d_in[0];
    const float* W     = (const float*)d_in[1];
    const float* bias  = (const float*)d_in[2];
    const float* gamma = (const float*)d_in[3];
    const float* beta  = (const float*)d_in[4];
    float* out = (float*)d_out;

    char* ws = (char*)d_ws;
    float*    dists  = (float*)(ws + OFF_DISTS);
    unsigned* ghist  = (unsigned*)(ws + OFF_HIST);
    double*   stats  = (double*)(ws + OFF_STATS);
    unsigned* med    = (unsigned*)(ws + OFF_MED);
    float*    signal = (float*)(ws + OFF_SIGNAL);
    unsigned long long* adj = (unsigned long long*)(ws + OFF_ADJ);

    // zero hist + stats (med is fully rewritten each call)
    hipMemsetAsync(ws + OFF_HIST, 0, 65536ull + 128ull, stream);

    k_dist    <<<dim3(8, 8, NBATCH),   256,  0, stream>>>(x, dists, stats);
    k_hist    <<<dim3(64, NBATCH),     256,  0, stream>>>(dists, stats, ghist);
    k_sel     <<<NBATCH,               256,  0, stream>>>(ghist, stats, med);
    k_adjstats<<<dim3(128, NBATCH),    256,  0, stream>>>(dists, med, adj, stats);
    k_cc      <<<NBATCH,               1024, 0, stream>>>(adj, med);
    k_signal  <<<NBATCH,               256,  0, stream>>>(stats, med, W, bias, signal);
    k_ln      <<<512,                  256,  0, stream>>>(x, signal, gamma, beta, out);
}

// Round 2
// 69.042 us; speedup vs baseline: 1.8968x; 1.8968x over previous
//
#include <hip/hip_runtime.h>
#include <math.h>

#define SDIM 512
#define DDIM 256
#define NBATCH 4
#define SSQ (SDIM*SDIM)            // 262144
#define MED_K ((SSQ-1)/2)          // 131071
#define NBINS 4096

// ---- workspace layout (bytes) ----
#define OFF_DISTS   0ull                               // 4 MB: float[4][512][512]
#define OFF_HIST    (4ull<<20)                         // 64 KB: uint[4][4096]
#define OFF_STATS   ((4ull<<20) + 65536ull)            // 128 B: per batch 4 doubles: sum, sumsq, (maxbits|conn)
#define OFF_MED     ((4ull<<20) + 65536ull + 128ull)   // 64 B: per batch 4 uint: -,-,thr_bits,ncomp
#define OFF_SIGNAL  ((4ull<<20) + 69632ull)            // 4 KB: float[4][256]
#define OFF_ADJ     ((4ull<<20) + 73728ull)            // 128 KB: u64[4][512][8]
#define OFF_NORMS   ((4ull<<20) + 73728ull + 131072ull) // 8 KB: float[4][512]

// ---------------------------------------------------------------------------
// 0) row squared-norms: wave per row
__global__ __launch_bounds__(256) void k_norms(const float* __restrict__ x,
                                               float* __restrict__ norms) {
    const int row = blockIdx.x * 4 + (threadIdx.x >> 6);   // 0..2047
    const int lane = threadIdx.x & 63;
    float4 v = *(const float4*)(x + (size_t)row * DDIM + lane * 4);
    float s = v.x * v.x + v.y * v.y + v.z * v.z + v.w * v.w;
#pragma unroll
    for (int off = 32; off; off >>= 1) s += __shfl_xor(s, off);
    if (lane == 0) norms[row] = s;
}

// ---------------------------------------------------------------------------
// 1) pairwise distances via d^2 = |a|^2 + |b|^2 - 2 a.b  (fma-only inner loop)
//    64x64 tile per block, 4x4 pairs per thread; block-reduced global max.
__global__ __launch_bounds__(256) void k_dist(const float* __restrict__ x,
                                              const float* __restrict__ norms,
                                              float* __restrict__ dists,
                                              double* __restrict__ stats) {
    const int b  = blockIdx.z;
    const int i0 = blockIdx.y * 64, j0 = blockIdx.x * 64;
    __shared__ float As[64][68];
    __shared__ float Bs[64][68];
    const int tid = threadIdx.x;
    const int tx = tid & 15, ty = tid >> 4;
    float acc[4][4] = {};
    const float* xb = x + (size_t)b * SDIM * DDIM;

    for (int kc = 0; kc < 4; ++kc) {
        const int k0 = kc * 64;
#pragma unroll
        for (int rr = 0; rr < 4; ++rr) {
            int r = ty + rr * 16;
            float4 a4 = *(const float4*)(xb + (size_t)(i0 + r) * DDIM + k0 + tx * 4);
            float4 b4 = *(const float4*)(xb + (size_t)(j0 + r) * DDIM + k0 + tx * 4);
            *(float4*)&As[r][tx * 4] = a4;
            *(float4*)&Bs[r][tx * 4] = b4;
        }
        __syncthreads();
#pragma unroll
        for (int kk = 0; kk < 16; ++kk) {
            float4 av[4], bv[4];
#pragma unroll
            for (int a = 0; a < 4; ++a) av[a] = *(const float4*)&As[ty * 4 + a][kk * 4];
#pragma unroll
            for (int c = 0; c < 4; ++c) bv[c] = *(const float4*)&Bs[tx + 16 * c][kk * 4];
#pragma unroll
            for (int a = 0; a < 4; ++a)
#pragma unroll
                for (int c = 0; c < 4; ++c) {
                    acc[a][c] = fmaf(av[a].x, bv[c].x, acc[a][c]);
                    acc[a][c] = fmaf(av[a].y, bv[c].y, acc[a][c]);
                    acc[a][c] = fmaf(av[a].z, bv[c].z, acc[a][c]);
                    acc[a][c] = fmaf(av[a].w, bv[c].w, acc[a][c]);
                }
        }
        __syncthreads();
    }

    const float* nb = norms + (size_t)b * SDIM;
    float ni[4], nj[4];
#pragma unroll
    for (int a = 0; a < 4; ++a) ni[a] = nb[i0 + ty * 4 + a];
#pragma unroll
    for (int c = 0; c < 4; ++c) nj[c] = nb[j0 + tx + 16 * c];

    float* db = dists + (size_t)b * SSQ;
    float bm = 0.f;
#pragma unroll
    for (int a = 0; a < 4; ++a) {
        int i = i0 + ty * 4 + a;
#pragma unroll
        for (int c = 0; c < 4; ++c) {
            int j = j0 + tx + 16 * c;
            float sq = fmaf(-2.0f, acc[a][c], ni[a] + nj[c]);
            float d  = sq > 0.f ? sqrtf(sq) : 0.f;
            if (i == j) d = 0.f;               // exact diagonal (cancellation guard)
            bm = fmaxf(bm, d);
            db[(size_t)i * SDIM + j] = d;
        }
    }
#pragma unroll
    for (int off = 32; off; off >>= 1) bm = fmaxf(bm, __shfl_xor(bm, off));
    __shared__ float wm[4];
    if ((tid & 63) == 0) wm[tid >> 6] = bm;
    __syncthreads();
    if (tid == 0) {
        float m = fmaxf(fmaxf(wm[0], wm[1]), fmaxf(wm[2], wm[3]));
        atomicMax((unsigned*)(stats + (size_t)b * 4 + 2), __float_as_uint(m));
    }
}

// ---------------------------------------------------------------------------
// 2) linear-bin histogram over [0, maxd], LDS-privatized.
__global__ __launch_bounds__(256) void k_hist(const float* __restrict__ dists,
                                              const double* __restrict__ stats,
                                              unsigned* __restrict__ ghist) {
    const int b = blockIdx.y;
    __shared__ unsigned lh[NBINS];
    const int tid = threadIdx.x;
    for (int t = tid; t < NBINS; t += 256) lh[t] = 0;
    __syncthreads();
    const float maxd = __uint_as_float(((const unsigned*)(stats + (size_t)b * 4 + 2))[0]);
    const float scale = (float)NBINS / maxd;
    const float* db = dists + (size_t)b * SSQ + (size_t)blockIdx.x * 4096;
#pragma unroll 4
    for (int t = 0; t < 16; ++t) {
        float d = db[t * 256 + tid];
        int bin = (int)(d * scale);
        bin = bin > (NBINS - 1) ? (NBINS - 1) : bin;
        atomicAdd(&lh[bin], 1u);
    }
    __syncthreads();
    unsigned* gh = ghist + (size_t)b * NBINS;
    for (int t = tid; t < NBINS; t += 256) if (lh[t]) atomicAdd(&gh[t], lh[t]);
}

// ---------------------------------------------------------------------------
// 3) select median bin -> thr (bin midpoint; error <= maxd/8192, harmless)
__global__ __launch_bounds__(256) void k_sel(const unsigned* __restrict__ ghist,
                                             const double* __restrict__ stats,
                                             unsigned* __restrict__ med) {
    const int b = blockIdx.x, tid = threadIdx.x;
    const unsigned* h = ghist + (size_t)b * NBINS;
    unsigned local = 0;
    for (int t = 0; t < 16; ++t) local += h[tid * 16 + t];
    __shared__ unsigned psum[256];
    psum[tid] = local;
    __syncthreads();
    for (int off = 1; off < 256; off <<= 1) {
        unsigned v = 0;
        if (tid >= off) v = psum[tid - off];
        __syncthreads();
        psum[tid] += v;
        __syncthreads();
    }
    const unsigned excl = psum[tid] - local;
    const unsigned k = MED_K;
    if (k >= excl && k < excl + local) {
        unsigned run = excl;
        int bucket = tid * 16;
        for (int t = 0; t < 16; ++t) {
            unsigned c = h[tid * 16 + t];
            if (k < run + c) { bucket = tid * 16 + t; break; }
            run += c;
        }
        const float maxd = __uint_as_float(((const unsigned*)(stats + (size_t)b * 4 + 2))[0]);
        const float thr = ((float)bucket + 0.5f) * (maxd / (float)NBINS);
        med[b * 4 + 2] = __float_as_uint(thr);
    }
}

// ---------------------------------------------------------------------------
// 4) adjacency bitmask build (ballot) + triu stats + edge count
__global__ __launch_bounds__(256) void k_adjstats(const float* __restrict__ dists,
                                                  const unsigned* __restrict__ med,
                                                  unsigned long long* __restrict__ adj,
                                                  double* __restrict__ stats) {
    const int b = blockIdx.y;
    const float thr = __uint_as_float(med[b * 4 + 2]);
    const int w = threadIdx.x >> 6, lane = threadIdx.x & 63;
    const int i = blockIdx.x * 4 + w;
    const float* row = dists + (size_t)b * SSQ + (size_t)i * SDIM;
    float fsum = 0.f, fsumsq = 0.f, fmaxv = 0.f;
    int conn = 0;
    unsigned long long words[8];
#pragma unroll
    for (int c = 0; c < 8; ++c) {
        int j = c * 64 + lane;
        float d = row[j];
        bool pred = (d < thr) && (j != i);
        words[c] = __ballot(pred ? 1 : 0);
        conn += pred ? 1 : 0;
        if (j >= i) { fsum += d; fsumsq += d * d; }
        fmaxv = fmaxf(fmaxv, d);
    }
    if (lane == 0) {
#pragma unroll
        for (int c = 0; c < 8; ++c) adj[((size_t)b * SDIM + i) * 8 + c] = words[c];
    }
    double s = (double)fsum, q = (double)fsumsq;
#pragma unroll
    for (int off = 32; off; off >>= 1) {
        s += __shfl_xor(s, off);
        q += __shfl_xor(q, off);
        fmaxv = fmaxf(fmaxv, __shfl_xor(fmaxv, off));
        conn += __shfl_xor(conn, off);
    }
    __shared__ double sh_s[4], sh_q[4];
    __shared__ float sh_m[4];
    __shared__ int sh_c[4];
    if (lane == 0) { sh_s[w] = s; sh_q[w] = q; sh_m[w] = fmaxv; sh_c[w] = conn; }
    __syncthreads();
    if (threadIdx.x == 0) {
        double S0 = sh_s[0] + sh_s[1] + sh_s[2] + sh_s[3];
        double Q0 = sh_q[0] + sh_q[1] + sh_q[2] + sh_q[3];
        float  M0 = fmaxf(fmaxf(sh_m[0], sh_m[1]), fmaxf(sh_m[2], sh_m[3]));
        unsigned C0 = (unsigned)(sh_c[0] + sh_c[1] + sh_c[2] + sh_c[3]);
        double* st = stats + (size_t)b * 4;
        atomicAdd(&st[0], S0);
        atomicAdd(&st[1], Q0);
        atomicMax((unsigned*)&st[2], __float_as_uint(M0));
        atomicAdd(((unsigned*)&st[2]) + 1, C0);
    }
}

// ---------------------------------------------------------------------------
// 5) connected components by ballot-BFS over the symmetric adjacency.
//    next_frontier[j] = (adjrow[j] & frontier) != 0 && !reached[j]
//    -> one __ballot per wave produces one 64-bit frontier word.
//    Component count = number of BFS restarts. One block (512 thr) per batch.
__global__ __launch_bounds__(512) void k_cc(const uint4* __restrict__ adj,
                                            unsigned* __restrict__ med) {
    const int b = blockIdx.x;
    __shared__ uint4 am[SDIM][4];                 // 32 KB: row bitmasks (16 u32 each)
    __shared__ unsigned frontW[16], reachW[16];
    __shared__ int s_next, s_ncomp, s_any;
    const int tid = threadIdx.x;
    const uint4* ab = adj + (size_t)b * SDIM * 4;
    for (int t = tid; t < SDIM * 4; t += 512) ((uint4*)am)[t] = ab[t];
    if (tid < 16) { frontW[tid] = 0u; reachW[tid] = 0u; }
    if (tid == 0) s_ncomp = 0;
    __syncthreads();

    bool myReached = false;                       // row == tid
    for (int comp = 0; comp < SDIM; ++comp) {
        if (tid == 0) {
            int s = -1;
            for (int w = 0; w < 16 && s < 0; ++w) {
                unsigned m = ~reachW[w];
                if (m) s = w * 32 + __ffs(m) - 1;
            }
            s_next = s;
            if (s >= 0) s_ncomp++;
        }
        __syncthreads();
        const int s = s_next;
        if (s < 0) break;
        if (tid < 16) {
            unsigned f = (tid == (s >> 5)) ? (1u << (s & 31)) : 0u;
            frontW[tid] = f;
            reachW[tid] |= f;
        }
        if (tid == s) myReached = true;
        __syncthreads();

        for (int it = 0; it < SDIM; ++it) {
            const uint4 f0 = *(const uint4*)&frontW[0];
            const uint4 f1 = *(const uint4*)&frontW[4];
            const uint4 f2 = *(const uint4*)&frontW[8];
            const uint4 f3 = *(const uint4*)&frontW[12];
            const uint4 r0 = am[tid][0], r1 = am[tid][1];
            const uint4 r2 = am[tid][2], r3 = am[tid][3];
            const unsigned inter =
                (r0.x & f0.x) | (r0.y & f0.y) | (r0.z & f0.z) | (r0.w & f0.w) |
                (r1.x & f1.x) | (r1.y & f1.y) | (r1.z & f1.z) | (r1.w & f1.w) |
                (r2.x & f2.x) | (r2.y & f2.y) | (r2.z & f2.z) | (r2.w & f2.w) |
                (r3.x & f3.x) | (r3.y & f3.y) | (r3.z & f3.z) | (r3.w & f3.w);
            const bool act = (inter != 0u) && !myReached;
            const unsigned long long bal = __ballot(act ? 1 : 0);
            __syncthreads();                       // frontW reads done
            if ((tid & 63) == 0) {
                const int wv = tid >> 6;
                frontW[wv * 2]     = (unsigned)bal;
                frontW[wv * 2 + 1] = (unsigned)(bal >> 32);
            }
            if (tid == 0) s_any = 0;
            __syncthreads();
            if (act) myReached = true;
            if (tid < 16) {
                unsigned nf = frontW[tid];
                reachW[tid] |= nf;
                if (nf) atomicOr(&s_any, 1);
            }
            __syncthreads();
            if (!s_any) break;
        }
    }
    if (tid == 0) med[b * 4 + 3] = (unsigned)s_ncomp;
}

// ---------------------------------------------------------------------------
// 6) topo features -> signal = topo @ W^T + bias
__global__ __launch_bounds__(256) void k_signal(const double* __restrict__ stats,
                                                const unsigned* __restrict__ med,
                                                const float* __restrict__ W,
                                                const float* __restrict__ bias,
                                                float* __restrict__ signal) {
    const int b = blockIdx.x, d = threadIdx.x;
    const double* st = stats + (size_t)b * 4;
    const double sum = st[0], sumsq = st[1];
    const unsigned maxbits = ((const unsigned*)&st[2])[0];
    const unsigned conn    = ((const unsigned*)&st[2])[1];
    const unsigned ncomp   = med[b * 4 + 3];
    const double cntf = (double)(SDIM * (SDIM + 1) / 2);
    const double mean = sum / cntf;
    double var = (sumsq - sum * sum / cntf) / (cntf - 1.0);
    var = var > 0.0 ? var : 0.0;
    const float t0 = (float)((double)conn / (double)(SDIM * (SDIM - 1)));
    const float t1 = (float)ncomp / (float)SDIM;
    const float t2 = (float)((double)conn / (double)(SDIM * SDIM));
    const float t3 = (float)mean;
    const float t4 = (float)sqrt(var);
    const float t6 = __uint_as_float(maxbits);
    const float* w = W + d * 8;
    float sig = bias[d] + t0 * w[0] + t1 * w[1] + t2 * w[2] + t3 * w[3] + t4 * w[4] + t6 * w[6];
    signal[b * DDIM + d] = sig;
}

// ---------------------------------------------------------------------------
// 7) residual + LayerNorm, wave per row (D=256 -> 4 floats/lane)
__global__ __launch_bounds__(256) void k_ln(const float* __restrict__ x,
                                            const float* __restrict__ signal,
                                            const float* __restrict__ gamma,
                                            const float* __restrict__ beta,
                                            float* __restrict__ out) {
    const int tid = threadIdx.x;
    const int w = tid >> 6, lane = tid & 63;
    const int row = blockIdx.x * 4 + w;          // 0..2047
    const int b = row >> 9;
    const float4 xv = *(const float4*)(x + (size_t)row * DDIM + lane * 4);
    const float4 sg = *(const float4*)(signal + (size_t)b * DDIM + lane * 4);
    float h0 = xv.x + sg.x, h1 = xv.y + sg.y, h2 = xv.z + sg.z, h3 = xv.w + sg.w;
    float s = h0 + h1 + h2 + h3;
#pragma unroll
    for (int off = 32; off; off >>= 1) s += __shfl_xor(s, off);
    const float mu = s * (1.0f / 256.0f);
    const float d0 = h0 - mu, d1 = h1 - mu, d2 = h2 - mu, d3 = h3 - mu;
    float q = d0 * d0 + d1 * d1 + d2 * d2 + d3 * d3;
#pragma unroll
    for (int off = 32; off; off >>= 1) q += __shfl_xor(q, off);
    const float var = q * (1.0f / 256.0f);
    const float r = 1.0f / sqrtf(var + 1e-5f);
    const float4 g  = *(const float4*)(gamma + lane * 4);
    const float4 be = *(const float4*)(beta + lane * 4);
    float4 o;
    o.x = d0 * r * g.x + be.x;
    o.y = d1 * r * g.y + be.y;
    o.z = d2 * r * g.z + be.z;
    o.w = d3 * r * g.w + be.w;
    *(float4*)(out + (size_t)row * DDIM + lane * 4) = o;
}

// ---------------------------------------------------------------------------
extern "C" void kernel_launch(void* const* d_in, const int* in_sizes, int n_in,
                              void* d_out, int out_size, void* d_ws, size_t ws_size,
                              hipStream_t stream) {
    (void)in_sizes; (void)n_in; (void)out_size; (void)ws_size;
    const float* x     = (const float*)d_in[0];
    const float* W     = (const float*)d_in[1];
    const float* bias  = (const float*)d_in[2];
    const float* gamma = (const float*)d_in[3];
    const float* beta  = (const float*)d_in[4];
    float* out = (float*)d_out;

    char* ws = (char*)d_ws;
    float*    dists  = (float*)(ws + OFF_DISTS);
    unsigned* ghist  = (unsigned*)(ws + OFF_HIST);
    double*   stats  = (double*)(ws + OFF_STATS);
    unsigned* med    = (unsigned*)(ws + OFF_MED);
    float*    signal = (float*)(ws + OFF_SIGNAL);
    unsigned long long* adj = (unsigned long long*)(ws + OFF_ADJ);
    float*    norms  = (float*)(ws + OFF_NORMS);

    // zero hist + stats (med is fully rewritten each call)
    hipMemsetAsync(ws + OFF_HIST, 0, 65536ull + 128ull, stream);

    k_norms   <<<512,                  256,  0, stream>>>(x, norms);
    k_dist    <<<dim3(8, 8, NBATCH),   256,  0, stream>>>(x, norms, dists, stats);
    k_hist    <<<dim3(64, NBATCH),     256,  0, stream>>>(dists, stats, ghist);
    k_sel     <<<NBATCH,               256,  0, stream>>>(ghist, stats, med);
    k_adjstats<<<dim3(128, NBATCH),    256,  0, stream>>>(dists, med, adj, stats);
    k_cc      <<<NBATCH,               512,  0, stream>>>((const uint4*)adj, med);
    k_signal  <<<NBATCH,               256,  0, stream>>>(stats, med, W, bias, signal);
    k_ln      <<<512,                  256,  0, stream>>>(x, signal, gamma, beta, out);
}

// Round 3
// 48.193 us; speedup vs baseline: 2.7175x; 1.4326x over previous
//
#include <hip/hip_runtime.h>
#include <math.h>

#define SDIM 512
#define DDIM 256
#define NBATCH 4
#define SSQ (SDIM*SDIM)            // 262144
#define MED_K ((SSQ-1)/2)          // 131071
#define NBINS 4096
#define HMAX 48.0f                 // fixed histogram range [0, HMAX)

// ---- workspace layout (bytes) ----
#define OFF_DISTS   0ull                               // 4 MB: float[4][512][512]
#define OFF_HIST    (4ull<<20)                         // 64 KB: uint[4][4096]
#define OFF_STATS   ((4ull<<20) + 65536ull)            // 128 B: per batch 4 doubles: sum, sumsq, (maxbits|conn)
#define OFF_MED     ((4ull<<20) + 65536ull + 128ull)   // 64 B: per batch 4 uint: -,-,thr_bits,ncomp
#define OFF_SIGNAL  ((4ull<<20) + 69632ull)            // 4 KB: float[4][256]
#define OFF_ADJ     ((4ull<<20) + 73728ull)            // 128 KB: u64[4][512][8]
#define OFF_NORMS   ((4ull<<20) + 73728ull + 131072ull) // 8 KB: float[4][512]
#define NZERO ((65536 + 128) / 4)                      // u32 words to zero (hist+stats)

// ---------------------------------------------------------------------------
// 0) row squared-norms (wave per row) + zero hist/stats region.
//    (hipMemsetAsync's fillBufferAligned cost ~40us per call -> do it ourselves)
__global__ __launch_bounds__(256) void k_init(const float* __restrict__ x,
                                              float* __restrict__ norms,
                                              unsigned* __restrict__ zbase) {
    const int idx = blockIdx.x * 256 + threadIdx.x;
    if (idx < NZERO) zbase[idx] = 0u;
    const int row = blockIdx.x * 4 + (threadIdx.x >> 6);   // 0..2047
    const int lane = threadIdx.x & 63;
    float4 v = *(const float4*)(x + (size_t)row * DDIM + lane * 4);
    float s = v.x * v.x + v.y * v.y + v.z * v.z + v.w * v.w;
#pragma unroll
    for (int off = 32; off; off >>= 1) s += __shfl_xor(s, off);
    if (lane == 0) norms[row] = s;
}

// ---------------------------------------------------------------------------
// 1) pairwise distances via d^2 = |a|^2 + |b|^2 - 2 a.b  (fma-only inner loop)
//    64x64 tile per block, 4x4 pairs per thread.
//    Fused: fixed-range LDS histogram, triu sum/sumsq, global max.
__global__ __launch_bounds__(256) void k_dist(const float* __restrict__ x,
                                              const float* __restrict__ norms,
                                              float* __restrict__ dists,
                                              double* __restrict__ stats,
                                              unsigned* __restrict__ ghist) {
    const int b  = blockIdx.z;
    const int i0 = blockIdx.y * 64, j0 = blockIdx.x * 64;
    __shared__ float As[64][68];
    __shared__ float Bs[64][68];
    __shared__ unsigned lh[NBINS];                 // 16 KB block-private hist
    const int tid = threadIdx.x;
    const int tx = tid & 15, ty = tid >> 4;
    float acc[4][4] = {};
    const float* xb = x + (size_t)b * SDIM * DDIM;

    for (int t = tid; t < NBINS; t += 256) lh[t] = 0u;

    for (int kc = 0; kc < 4; ++kc) {
        const int k0 = kc * 64;
#pragma unroll
        for (int rr = 0; rr < 4; ++rr) {
            int r = ty + rr * 16;
            float4 a4 = *(const float4*)(xb + (size_t)(i0 + r) * DDIM + k0 + tx * 4);
            float4 b4 = *(const float4*)(xb + (size_t)(j0 + r) * DDIM + k0 + tx * 4);
            *(float4*)&As[r][tx * 4] = a4;
            *(float4*)&Bs[r][tx * 4] = b4;
        }
        __syncthreads();
#pragma unroll
        for (int kk = 0; kk < 16; ++kk) {
            float4 av[4], bv[4];
#pragma unroll
            for (int a = 0; a < 4; ++a) av[a] = *(const float4*)&As[ty * 4 + a][kk * 4];
#pragma unroll
            for (int c = 0; c < 4; ++c) bv[c] = *(const float4*)&Bs[tx + 16 * c][kk * 4];
#pragma unroll
            for (int a = 0; a < 4; ++a)
#pragma unroll
                for (int c = 0; c < 4; ++c) {
                    acc[a][c] = fmaf(av[a].x, bv[c].x, acc[a][c]);
                    acc[a][c] = fmaf(av[a].y, bv[c].y, acc[a][c]);
                    acc[a][c] = fmaf(av[a].z, bv[c].z, acc[a][c]);
                    acc[a][c] = fmaf(av[a].w, bv[c].w, acc[a][c]);
                }
        }
        __syncthreads();
    }

    const float* nb = norms + (size_t)b * SDIM;
    float ni[4], nj[4];
#pragma unroll
    for (int a = 0; a < 4; ++a) ni[a] = nb[i0 + ty * 4 + a];
#pragma unroll
    for (int c = 0; c < 4; ++c) nj[c] = nb[j0 + tx + 16 * c];

    float* db = dists + (size_t)b * SSQ;
    const float hscale = (float)NBINS / HMAX;
    float bm = 0.f, fsum = 0.f, fsumsq = 0.f;
#pragma unroll
    for (int a = 0; a < 4; ++a) {
        int i = i0 + ty * 4 + a;
#pragma unroll
        for (int c = 0; c < 4; ++c) {
            int j = j0 + tx + 16 * c;
            float sq = fmaf(-2.0f, acc[a][c], ni[a] + nj[c]);
            float d  = sq > 0.f ? sqrtf(sq) : 0.f;
            if (i == j) d = 0.f;               // exact diagonal (cancellation guard)
            bm = fmaxf(bm, d);
            db[(size_t)i * SDIM + j] = d;
            int bin = (int)(d * hscale);
            bin = bin > (NBINS - 1) ? (NBINS - 1) : bin;
            atomicAdd(&lh[bin], 1u);
            if (j >= i) { fsum += d; fsumsq += d * d; }
        }
    }
    // block reductions
    double s = (double)fsum, q = (double)fsumsq;
#pragma unroll
    for (int off = 32; off; off >>= 1) {
        bm = fmaxf(bm, __shfl_xor(bm, off));
        s += __shfl_xor(s, off);
        q += __shfl_xor(q, off);
    }
    __shared__ float wm[4];
    __shared__ double ws_[4], wq[4];
    if ((tid & 63) == 0) { wm[tid >> 6] = bm; ws_[tid >> 6] = s; wq[tid >> 6] = q; }
    __syncthreads();
    if (tid == 0) {
        double* st = stats + (size_t)b * 4;
        float m = fmaxf(fmaxf(wm[0], wm[1]), fmaxf(wm[2], wm[3]));
        atomicMax((unsigned*)(st + 2), __float_as_uint(m));
        atomicAdd(&st[0], ws_[0] + ws_[1] + ws_[2] + ws_[3]);
        atomicAdd(&st[1], wq[0] + wq[1] + wq[2] + wq[3]);
    }
    // merge block hist into per-batch global hist
    unsigned* gh = ghist + (size_t)b * NBINS;
    for (int t = tid; t < NBINS; t += 256) {
        unsigned v = lh[t];
        if (v) atomicAdd(&gh[t], v);
    }
}

// ---------------------------------------------------------------------------
// 2) select median bin -> thr (fixed range; error <= HMAX/NBINS/2, harmless)
__global__ __launch_bounds__(256) void k_sel(const unsigned* __restrict__ ghist,
                                             unsigned* __restrict__ med) {
    const int b = blockIdx.x, tid = threadIdx.x;
    const unsigned* h = ghist + (size_t)b * NBINS;
    unsigned local = 0;
    for (int t = 0; t < 16; ++t) local += h[tid * 16 + t];
    __shared__ unsigned psum[256];
    psum[tid] = local;
    __syncthreads();
    for (int off = 1; off < 256; off <<= 1) {
        unsigned v = 0;
        if (tid >= off) v = psum[tid - off];
        __syncthreads();
        psum[tid] += v;
        __syncthreads();
    }
    const unsigned excl = psum[tid] - local;
    const unsigned k = MED_K;
    if (k >= excl && k < excl + local) {
        unsigned run = excl;
        int bucket = tid * 16;
        for (int t = 0; t < 16; ++t) {
            unsigned c = h[tid * 16 + t];
            if (k < run + c) { bucket = tid * 16 + t; break; }
            run += c;
        }
        const float thr = ((float)bucket + 0.5f) * (HMAX / (float)NBINS);
        med[b * 4 + 2] = __float_as_uint(thr);
    }
}

// ---------------------------------------------------------------------------
// 3) adjacency bitmask build (ballot) + edge count
__global__ __launch_bounds__(256) void k_adjstats(const float* __restrict__ dists,
                                                  const unsigned* __restrict__ med,
                                                  unsigned long long* __restrict__ adj,
                                                  double* __restrict__ stats) {
    const int b = blockIdx.y;
    const float thr = __uint_as_float(med[b * 4 + 2]);
    const int w = threadIdx.x >> 6, lane = threadIdx.x & 63;
    const int i = blockIdx.x * 4 + w;
    const float* row = dists + (size_t)b * SSQ + (size_t)i * SDIM;
    int conn = 0;
    unsigned long long words[8];
#pragma unroll
    for (int c = 0; c < 8; ++c) {
        int j = c * 64 + lane;
        float d = row[j];
        bool pred = (d < thr) && (j != i);
        words[c] = __ballot(pred ? 1 : 0);
        conn += pred ? 1 : 0;
    }
    if (lane == 0) {
#pragma unroll
        for (int c = 0; c < 8; ++c) adj[((size_t)b * SDIM + i) * 8 + c] = words[c];
    }
#pragma unroll
    for (int off = 32; off; off >>= 1) conn += __shfl_xor(conn, off);
    __shared__ int sh_c[4];
    if (lane == 0) sh_c[w] = conn;
    __syncthreads();
    if (threadIdx.x == 0) {
        unsigned C0 = (unsigned)(sh_c[0] + sh_c[1] + sh_c[2] + sh_c[3]);
        atomicAdd(((unsigned*)(stats + (size_t)b * 4 + 2)) + 1, C0);
    }
}

// ---------------------------------------------------------------------------
// 4) connected components by ballot-BFS over the symmetric adjacency.
__global__ __launch_bounds__(512) void k_cc(const uint4* __restrict__ adj,
                                            unsigned* __restrict__ med) {
    const int b = blockIdx.x;
    __shared__ uint4 am[SDIM][4];                 // 32 KB: row bitmasks (16 u32 each)
    __shared__ unsigned frontW[16], reachW[16];
    __shared__ int s_next, s_ncomp, s_any;
    const int tid = threadIdx.x;
    const uint4* ab = adj + (size_t)b * SDIM * 4;
    for (int t = tid; t < SDIM * 4; t += 512) ((uint4*)am)[t] = ab[t];
    if (tid < 16) { frontW[tid] = 0u; reachW[tid] = 0u; }
    if (tid == 0) s_ncomp = 0;
    __syncthreads();

    bool myReached = false;                       // row == tid
    for (int comp = 0; comp < SDIM; ++comp) {
        if (tid == 0) {
            int s = -1;
            for (int w = 0; w < 16 && s < 0; ++w) {
                unsigned m = ~reachW[w];
                if (m) s = w * 32 + __ffs(m) - 1;
            }
            s_next = s;
            if (s >= 0) s_ncomp++;
        }
        __syncthreads();
        const int s = s_next;
        if (s < 0) break;
        if (tid < 16) {
            unsigned f = (tid == (s >> 5)) ? (1u << (s & 31)) : 0u;
            frontW[tid] = f;
            reachW[tid] |= f;
        }
        if (tid == s) myReached = true;
        __syncthreads();

        for (int it = 0; it < SDIM; ++it) {
            const uint4 f0 = *(const uint4*)&frontW[0];
            const uint4 f1 = *(const uint4*)&frontW[4];
            const uint4 f2 = *(const uint4*)&frontW[8];
            const uint4 f3 = *(const uint4*)&frontW[12];
            const uint4 r0 = am[tid][0], r1 = am[tid][1];
            const uint4 r2 = am[tid][2], r3 = am[tid][3];
            const unsigned inter =
                (r0.x & f0.x) | (r0.y & f0.y) | (r0.z & f0.z) | (r0.w & f0.w) |
                (r1.x & f1.x) | (r1.y & f1.y) | (r1.z & f1.z) | (r1.w & f1.w) |
                (r2.x & f2.x) | (r2.y & f2.y) | (r2.z & f2.z) | (r2.w & f2.w) |
                (r3.x & f3.x) | (r3.y & f3.y) | (r3.z & f3.z) | (r3.w & f3.w);
            const bool act = (inter != 0u) && !myReached;
            const unsigned long long bal = __ballot(act ? 1 : 0);
            __syncthreads();                       // frontW reads done
            if ((tid & 63) == 0) {
                const int wv = tid >> 6;
                frontW[wv * 2]     = (unsigned)bal;
                frontW[wv * 2 + 1] = (unsigned)(bal >> 32);
            }
            if (tid == 0) s_any = 0;
            __syncthreads();
            if (act) myReached = true;
            if (tid < 16) {
                unsigned nf = frontW[tid];
                reachW[tid] |= nf;
                if (nf) atomicOr(&s_any, 1);
            }
            __syncthreads();
            if (!s_any) break;
        }
    }
    if (tid == 0) med[b * 4 + 3] = (unsigned)s_ncomp;
}

// ---------------------------------------------------------------------------
// 5) topo features -> signal = topo @ W^T + bias
__global__ __launch_bounds__(256) void k_signal(const double* __restrict__ stats,
                                                const unsigned* __restrict__ med,
                                                const float* __restrict__ W,
                                                const float* __restrict__ bias,
                                                float* __restrict__ signal) {
    const int b = blockIdx.x, d = threadIdx.x;
    const double* st = stats + (size_t)b * 4;
    const double sum = st[0], sumsq = st[1];
    const unsigned maxbits = ((const unsigned*)&st[2])[0];
    const unsigned conn    = ((const unsigned*)&st[2])[1];
    const unsigned ncomp   = med[b * 4 + 3];
    const double cntf = (double)(SDIM * (SDIM + 1) / 2);
    const double mean = sum / cntf;
    double var = (sumsq - sum * sum / cntf) / (cntf - 1.0);
    var = var > 0.0 ? var : 0.0;
    const float t0 = (float)((double)conn / (double)(SDIM * (SDIM - 1)));
    const float t1 = (float)ncomp / (float)SDIM;
    const float t2 = (float)((double)conn / (double)(SDIM * SDIM));
    const float t3 = (float)mean;
    const float t4 = (float)sqrt(var);
    const float t6 = __uint_as_float(maxbits);
    const float* w = W + d * 8;
    float sig = bias[d] + t0 * w[0] + t1 * w[1] + t2 * w[2] + t3 * w[3] + t4 * w[4] + t6 * w[6];
    signal[b * DDIM + d] = sig;
}

// ---------------------------------------------------------------------------
// 6) residual + LayerNorm, wave per row (D=256 -> 4 floats/lane)
__global__ __launch_bounds__(256) void k_ln(const float* __restrict__ x,
                                            const float* __restrict__ signal,
                                            const float* __restrict__ gamma,
                                            const float* __restrict__ beta,
                                            float* __restrict__ out) {
    const int tid = threadIdx.x;
    const int w = tid >> 6, lane = tid & 63;
    const int row = blockIdx.x * 4 + w;          // 0..2047
    const int b = row >> 9;
    const float4 xv = *(const float4*)(x + (size_t)row * DDIM + lane * 4);
    const float4 sg = *(const float4*)(signal + (size_t)b * DDIM + lane * 4);
    float h0 = xv.x + sg.x, h1 = xv.y + sg.y, h2 = xv.z + sg.z, h3 = xv.w + sg.w;
    float s = h0 + h1 + h2 + h3;
#pragma unroll
    for (int off = 32; off; off >>= 1) s += __shfl_xor(s, off);
    const float mu = s * (1.0f / 256.0f);
    const float d0 = h0 - mu, d1 = h1 - mu, d2 = h2 - mu, d3 = h3 - mu;
    float q = d0 * d0 + d1 * d1 + d2 * d2 + d3 * d3;
#pragma unroll
    for (int off = 32; off; off >>= 1) q += __shfl_xor(q, off);
    const float var = q * (1.0f / 256.0f);
    const float r = 1.0f / sqrtf(var + 1e-5f);
    const float4 g  = *(const float4*)(gamma + lane * 4);
    const float4 be = *(const float4*)(beta + lane * 4);
    float4 o;
    o.x = d0 * r * g.x + be.x;
    o.y = d1 * r * g.y + be.y;
    o.z = d2 * r * g.z + be.z;
    o.w = d3 * r * g.w + be.w;
    *(float4*)(out + (size_t)row * DDIM + lane * 4) = o;
}

// ---------------------------------------------------------------------------
extern "C" void kernel_launch(void* const* d_in, const int* in_sizes, int n_in,
                              void* d_out, int out_size, void* d_ws, size_t ws_size,
                              hipStream_t stream) {
    (void)in_sizes; (void)n_in; (void)out_size; (void)ws_size;
    const float* x     = (const float*)d_in[0];
    const float* W     = (const float*)d_in[1];
    const float* bias  = (const float*)d_in[2];
    const float* gamma = (const float*)d_in[3];
    const float* beta  = (const float*)d_in[4];
    float* out = (float*)d_out;

    char* ws = (char*)d_ws;
    float*    dists  = (float*)(ws + OFF_DISTS);
    unsigned* ghist  = (unsigned*)(ws + OFF_HIST);
    double*   stats  = (double*)(ws + OFF_STATS);
    unsigned* med    = (unsigned*)(ws + OFF_MED);
    float*    signal = (float*)(ws + OFF_SIGNAL);
    unsigned long long* adj = (unsigned long long*)(ws + OFF_ADJ);
    float*    norms  = (float*)(ws + OFF_NORMS);

    k_init    <<<512,                  256,  0, stream>>>(x, norms, (unsigned*)(ws + OFF_HIST));
    k_dist    <<<dim3(8, 8, NBATCH),   256,  0, stream>>>(x, norms, dists, stats, ghist);
    k_sel     <<<NBATCH,               256,  0, stream>>>(ghist, med);
    k_adjstats<<<dim3(128, NBATCH),    256,  0, stream>>>(dists, med, adj, stats);
    k_cc      <<<NBATCH,               512,  0, stream>>>((const uint4*)adj, med);
    k_signal  <<<NBATCH,               256,  0, stream>>>(stats, med, W, bias, signal);
    k_ln      <<<512,                  256,  0, stream>>>(x, signal, gamma, beta, out);
}

// Round 4
// 48.085 us; speedup vs baseline: 2.7236x; 1.0022x over previous
//
#include <hip/hip_runtime.h>
#include <math.h>

#define SDIM 512
#define DDIM 256
#define NBATCH 4
#define SSQ (SDIM*SDIM)            // 262144
#define MED_K ((SSQ-1)/2)          // 131071
#define NBINS 4096
#define HMAX 48.0f                 // fixed histogram range [0, HMAX)

// ---- workspace layout (bytes) ----
#define OFF_DISTS   0ull                               // 4 MB: float[4][512][512]
#define OFF_HIST    (4ull<<20)                         // 64 KB: uint[4][4096]
#define OFF_STATS   ((4ull<<20) + 65536ull)            // 128 B: per batch 4 doubles: sum, sumsq, (maxbits|conn)
#define OFF_SIGNAL  ((4ull<<20) + 65664ull)            // 4 KB: float[4][256]
#define OFF_ADJ     ((4ull<<20) + 69760ull)            // 128 KB: u64[4][512][8]
#define NZERO ((65536 + 128) / 4)                      // u32 words to zero (hist+stats)

// ---------------------------------------------------------------------------
// 0) zero hist+stats (65 blocks; hipMemsetAsync's fill kernel costs ~40us)
__global__ __launch_bounds__(256) void k_zero(unsigned* __restrict__ z) {
    const int i = blockIdx.x * 256 + threadIdx.x;
    if (i < NZERO) z[i] = 0u;
}

// ---------------------------------------------------------------------------
// 1) pairwise distances via d^2 = |a|^2 + |b|^2 - 2 a.b  (fma-only inner loop)
//    64x64 tile per block, 4x4 pairs per thread. Row norms computed in-block
//    during staging (16-lane butterfly; identical reduce tree in every block
//    -> bitwise-identical norms -> exactly symmetric matrix).
//    Fused: fixed-range LDS histogram, triu sum/sumsq, global max.
__global__ __launch_bounds__(256) void k_dist(const float* __restrict__ x,
                                              float* __restrict__ dists,
                                              double* __restrict__ stats,
                                              unsigned* __restrict__ ghist) {
    const int b  = blockIdx.z;
    const int i0 = blockIdx.y * 64, j0 = blockIdx.x * 64;
    __shared__ float As[64][68];
    __shared__ float Bs[64][68];
    __shared__ unsigned lh[NBINS];                 // 16 KB block-private hist
    __shared__ float nA[64], nB[64];
    const int tid = threadIdx.x;
    const int tx = tid & 15, ty = tid >> 4;
    float acc[4][4] = {};
    float na[4] = {0.f, 0.f, 0.f, 0.f}, nb_[4] = {0.f, 0.f, 0.f, 0.f};
    const float* xb = x + (size_t)b * SDIM * DDIM;

    for (int t = tid; t < NBINS; t += 256) lh[t] = 0u;

    for (int kc = 0; kc < 4; ++kc) {
        const int k0 = kc * 64;
#pragma unroll
        for (int rr = 0; rr < 4; ++rr) {
            int r = ty + rr * 16;
            float4 a4 = *(const float4*)(xb + (size_t)(i0 + r) * DDIM + k0 + tx * 4);
            float4 b4 = *(const float4*)(xb + (size_t)(j0 + r) * DDIM + k0 + tx * 4);
            *(float4*)&As[r][tx * 4] = a4;
            *(float4*)&Bs[r][tx * 4] = b4;
            float sa = a4.x * a4.x + a4.y * a4.y + a4.z * a4.z + a4.w * a4.w;
            float sb = b4.x * b4.x + b4.y * b4.y + b4.z * b4.z + b4.w * b4.w;
#pragma unroll
            for (int m = 1; m < 16; m <<= 1) {
                sa += __shfl_xor(sa, m);
                sb += __shfl_xor(sb, m);
            }
            na[rr] += sa;                          // full row-sum in all 16 lanes
            nb_[rr] += sb;
        }
        __syncthreads();
#pragma unroll
        for (int kk = 0; kk < 16; ++kk) {
            float4 av[4], bv[4];
#pragma unroll
            for (int a = 0; a < 4; ++a) av[a] = *(const float4*)&As[ty * 4 + a][kk * 4];
#pragma unroll
            for (int c = 0; c < 4; ++c) bv[c] = *(const float4*)&Bs[tx + 16 * c][kk * 4];
#pragma unroll
            for (int a = 0; a < 4; ++a)
#pragma unroll
                for (int c = 0; c < 4; ++c) {
                    acc[a][c] = fmaf(av[a].x, bv[c].x, acc[a][c]);
                    acc[a][c] = fmaf(av[a].y, bv[c].y, acc[a][c]);
                    acc[a][c] = fmaf(av[a].z, bv[c].z, acc[a][c]);
                    acc[a][c] = fmaf(av[a].w, bv[c].w, acc[a][c]);
                }
        }
        __syncthreads();
    }
    if (tx == 0) {
#pragma unroll
        for (int rr = 0; rr < 4; ++rr) { nA[ty + rr * 16] = na[rr]; nB[ty + rr * 16] = nb_[rr]; }
    }
    __syncthreads();

    float ni[4], nj[4];
#pragma unroll
    for (int a = 0; a < 4; ++a) ni[a] = nA[ty * 4 + a];
#pragma unroll
    for (int c = 0; c < 4; ++c) nj[c] = nB[tx + 16 * c];

    float* db = dists + (size_t)b * SSQ;
    const float hscale = (float)NBINS / HMAX;
    float bm = 0.f, fsum = 0.f, fsumsq = 0.f;
#pragma unroll
    for (int a = 0; a < 4; ++a) {
        int i = i0 + ty * 4 + a;
#pragma unroll
        for (int c = 0; c < 4; ++c) {
            int j = j0 + tx + 16 * c;
            float sq = fmaf(-2.0f, acc[a][c], ni[a] + nj[c]);
            float d  = sq > 0.f ? sqrtf(sq) : 0.f;
            if (i == j) d = 0.f;               // exact diagonal (cancellation guard)
            bm = fmaxf(bm, d);
            db[(size_t)i * SDIM + j] = d;
            int bin = (int)(d * hscale);
            bin = bin > (NBINS - 1) ? (NBINS - 1) : bin;
            atomicAdd(&lh[bin], 1u);
            if (j >= i) { fsum += d; fsumsq += d * d; }
        }
    }
    // block reductions
    double s = (double)fsum, q = (double)fsumsq;
#pragma unroll
    for (int off = 32; off; off >>= 1) {
        bm = fmaxf(bm, __shfl_xor(bm, off));
        s += __shfl_xor(s, off);
        q += __shfl_xor(q, off);
    }
    __shared__ float wm[4];
    __shared__ double ws_[4], wq[4];
    if ((tid & 63) == 0) { wm[tid >> 6] = bm; ws_[tid >> 6] = s; wq[tid >> 6] = q; }
    __syncthreads();
    if (tid == 0) {
        double* st = stats + (size_t)b * 4;
        float m = fmaxf(fmaxf(wm[0], wm[1]), fmaxf(wm[2], wm[3]));
        atomicMax((unsigned*)(st + 2), __float_as_uint(m));
        atomicAdd(&st[0], ws_[0] + ws_[1] + ws_[2] + ws_[3]);
        atomicAdd(&st[1], wq[0] + wq[1] + wq[2] + wq[3]);
    }
    // merge block hist into per-batch global hist
    unsigned* gh = ghist + (size_t)b * NBINS;
    for (int t = tid; t < NBINS; t += 256) {
        unsigned v = lh[t];
        if (v) atomicAdd(&gh[t], v);
    }
}

// ---------------------------------------------------------------------------
// 2) adjacency: inline median scan (redundant per block, ghist is L2-hot),
//    then ballot bitmask build + edge count.
__global__ __launch_bounds__(256) void k_adj(const float* __restrict__ dists,
                                             const unsigned* __restrict__ ghist,
                                             unsigned long long* __restrict__ adj,
                                             double* __restrict__ stats) {
    const int b = blockIdx.y, tid = threadIdx.x;
    // --- inline median selection ---
    const unsigned* h = ghist + (size_t)b * NBINS;
    unsigned lcnt[16];
    unsigned local = 0;
#pragma unroll
    for (int t = 0; t < 16; ++t) { lcnt[t] = h[tid * 16 + t]; local += lcnt[t]; }
    __shared__ unsigned psum[256];
    __shared__ float sthr;
    psum[tid] = local;
    __syncthreads();
    for (int off = 1; off < 256; off <<= 1) {
        unsigned v = 0;
        if (tid >= off) v = psum[tid - off];
        __syncthreads();
        psum[tid] += v;
        __syncthreads();
    }
    const unsigned excl = psum[tid] - local;
    if (MED_K >= excl && MED_K < excl + local) {
        unsigned run = excl;
        int bucket = tid * 16;
        for (int t = 0; t < 16; ++t) {
            if (MED_K < run + lcnt[t]) { bucket = tid * 16 + t; break; }
            run += lcnt[t];
        }
        sthr = ((float)bucket + 0.5f) * (HMAX / (float)NBINS);
    }
    __syncthreads();
    const float thr = sthr;

    // --- adjacency + conn ---
    const int w = tid >> 6, lane = tid & 63;
    const int i = blockIdx.x * 4 + w;
    const float* row = dists + (size_t)b * SSQ + (size_t)i * SDIM;
    int conn = 0;
    unsigned long long words[8];
#pragma unroll
    for (int c = 0; c < 8; ++c) {
        int j = c * 64 + lane;
        float d = row[j];
        bool pred = (d < thr) && (j != i);
        words[c] = __ballot(pred ? 1 : 0);
        conn += pred ? 1 : 0;
    }
    if (lane == 0) {
#pragma unroll
        for (int c = 0; c < 8; ++c) adj[((size_t)b * SDIM + i) * 8 + c] = words[c];
    }
#pragma unroll
    for (int off = 32; off; off >>= 1) conn += __shfl_xor(conn, off);
    __shared__ int sh_c[4];
    if (lane == 0) sh_c[w] = conn;
    __syncthreads();
    if (tid == 0) {
        unsigned C0 = (unsigned)(sh_c[0] + sh_c[1] + sh_c[2] + sh_c[3]);
        atomicAdd(((unsigned*)(stats + (size_t)b * 4 + 2)) + 1, C0);
    }
}

// ---------------------------------------------------------------------------
// 3) connected components by ballot-BFS + topo-feature matvec (signal).
__global__ __launch_bounds__(512) void k_ccsig(const uint4* __restrict__ adj,
                                               const double* __restrict__ stats,
                                               const float* __restrict__ W,
                                               const float* __restrict__ bias,
                                               float* __restrict__ signal) {
    const int b = blockIdx.x;
    __shared__ uint4 am[SDIM][4];                 // 32 KB: row bitmasks (16 u32 each)
    __shared__ unsigned frontW[16], reachW[16];
    __shared__ int s_next, s_ncomp, s_any;
    const int tid = threadIdx.x;
    const uint4* ab = adj + (size_t)b * SDIM * 4;
    for (int t = tid; t < SDIM * 4; t += 512) ((uint4*)am)[t] = ab[t];
    if (tid < 16) { frontW[tid] = 0u; reachW[tid] = 0u; }
    if (tid == 0) s_ncomp = 0;
    __syncthreads();

    bool myReached = false;                       // row == tid
    for (int comp = 0; comp < SDIM; ++comp) {
        if (tid == 0) {
            int s = -1;
            for (int w = 0; w < 16 && s < 0; ++w) {
                unsigned m = ~reachW[w];
                if (m) s = w * 32 + __ffs(m) - 1;
            }
            s_next = s;
            if (s >= 0) s_ncomp++;
        }
        __syncthreads();
        const int s = s_next;
        if (s < 0) break;
        if (tid < 16) {
            unsigned f = (tid == (s >> 5)) ? (1u << (s & 31)) : 0u;
            frontW[tid] = f;
            reachW[tid] |= f;
        }
        if (tid == s) myReached = true;
        __syncthreads();

        for (int it = 0; it < SDIM; ++it) {
            const uint4 f0 = *(const uint4*)&frontW[0];
            const uint4 f1 = *(const uint4*)&frontW[4];
            const uint4 f2 = *(const uint4*)&frontW[8];
            const uint4 f3 = *(const uint4*)&frontW[12];
            const uint4 r0 = am[tid][0], r1 = am[tid][1];
            const uint4 r2 = am[tid][2], r3 = am[tid][3];
            const unsigned inter =
                (r0.x & f0.x) | (r0.y & f0.y) | (r0.z & f0.z) | (r0.w & f0.w) |
                (r1.x & f1.x) | (r1.y & f1.y) | (r1.z & f1.z) | (r1.w & f1.w) |
                (r2.x & f2.x) | (r2.y & f2.y) | (r2.z & f2.z) | (r2.w & f2.w) |
                (r3.x & f3.x) | (r3.y & f3.y) | (r3.z & f3.z) | (r3.w & f3.w);
            const bool act = (inter != 0u) && !myReached;
            const unsigned long long bal = __ballot(act ? 1 : 0);
            __syncthreads();                       // frontW reads done
            if ((tid & 63) == 0) {
                const int wv = tid >> 6;
                frontW[wv * 2]     = (unsigned)bal;
                frontW[wv * 2 + 1] = (unsigned)(bal >> 32);
            }
            if (tid == 0) s_any = 0;
            __syncthreads();
            if (act) myReached = true;
            if (tid < 16) {
                unsigned nf = frontW[tid];
                reachW[tid] |= nf;
                if (nf) atomicOr(&s_any, 1);
            }
            __syncthreads();
            if (!s_any) break;
        }
    }
    __syncthreads();

    // --- topo features -> signal = topo @ W^T + bias (threads 0..255) ---
    if (tid < DDIM) {
        const double* st = stats + (size_t)b * 4;
        const double sum = st[0], sumsq = st[1];
        const unsigned maxbits = ((const unsigned*)&st[2])[0];
        const unsigned conn    = ((const unsigned*)&st[2])[1];
        const double cntf = (double)(SDIM * (SDIM + 1) / 2);
        const double mean = sum / cntf;
        double var = (sumsq - sum * sum / cntf) / (cntf - 1.0);
        var = var > 0.0 ? var : 0.0;
        const float t0 = (float)((double)conn / (double)(SDIM * (SDIM - 1)));
        const float t1 = (float)s_ncomp / (float)SDIM;
        const float t2 = (float)((double)conn / (double)(SDIM * SDIM));
        const float t3 = (float)mean;
        const float t4 = (float)sqrt(var);
        const float t6 = __uint_as_float(maxbits);
        const float* w = W + tid * 8;
        signal[b * DDIM + tid] = bias[tid] + t0 * w[0] + t1 * w[1] + t2 * w[2]
                               + t3 * w[3] + t4 * w[4] + t6 * w[6];
    }
}

// ---------------------------------------------------------------------------
// 4) residual + LayerNorm, wave per row (D=256 -> 4 floats/lane)
__global__ __launch_bounds__(256) void k_ln(const float* __restrict__ x,
                                            const float* __restrict__ signal,
                                            const float* __restrict__ gamma,
                                            const float* __restrict__ beta,
                                            float* __restrict__ out) {
    const int tid = threadIdx.x;
    const int w = tid >> 6, lane = tid & 63;
    const int row = blockIdx.x * 4 + w;          // 0..2047
    const int b = row >> 9;
    const float4 xv = *(const float4*)(x + (size_t)row * DDIM + lane * 4);
    const float4 sg = *(const float4*)(signal + (size_t)b * DDIM + lane * 4);
    float h0 = xv.x + sg.x, h1 = xv.y + sg.y, h2 = xv.z + sg.z, h3 = xv.w + sg.w;
    float s = h0 + h1 + h2 + h3;
#pragma unroll
    for (int off = 32; off; off >>= 1) s += __shfl_xor(s, off);
    const float mu = s * (1.0f / 256.0f);
    const float d0 = h0 - mu, d1 = h1 - mu, d2 = h2 - mu, d3 = h3 - mu;
    float q = d0 * d0 + d1 * d1 + d2 * d2 + d3 * d3;
#pragma unroll
    for (int off = 32; off; off >>= 1) q += __shfl_xor(q, off);
    const float var = q * (1.0f / 256.0f);
    const float r = 1.0f / sqrtf(var + 1e-5f);
    const float4 g  = *(const float4*)(gamma + lane * 4);
    const float4 be = *(const float4*)(beta + lane * 4);
    float4 o;
    o.x = d0 * r * g.x + be.x;
    o.y = d1 * r * g.y + be.y;
    o.z = d2 * r * g.z + be.z;
    o.w = d3 * r * g.w + be.w;
    *(float4*)(out + (size_t)row * DDIM + lane * 4) = o;
}

// ---------------------------------------------------------------------------
extern "C" void kernel_launch(void* const* d_in, const int* in_sizes, int n_in,
                              void* d_out, int out_size, void* d_ws, size_t ws_size,
                              hipStream_t stream) {
    (void)in_sizes; (void)n_in; (void)out_size; (void)ws_size;
    const float* x     = (const float*)d_in[0];
    const float* W     = (const float*)d_in[1];
    const float* bias  = (const float*)d_in[2];
    const float* gamma = (const float*)d_in[3];
    const float* beta  = (const float*)d_in[4];
    float* out = (float*)d_out;

    char* ws = (char*)d_ws;
    float*    dists  = (float*)(ws + OFF_DISTS);
    unsigned* ghist  = (unsigned*)(ws + OFF_HIST);
    double*   stats  = (double*)(ws + OFF_STATS);
    float*    signal = (float*)(ws + OFF_SIGNAL);
    unsigned long long* adj = (unsigned long long*)(ws + OFF_ADJ);

    k_zero  <<<(NZERO + 255) / 256,  256, 0, stream>>>((unsigned*)(ws + OFF_HIST));
    k_dist  <<<dim3(8, 8, NBATCH),   256, 0, stream>>>(x, dists, stats, ghist);
    k_adj   <<<dim3(128, NBATCH),    256, 0, stream>>>(dists, ghist, adj, stats);
    k_ccsig <<<NBATCH,               512, 0, stream>>>((const uint4*)adj, stats, W, bias, signal);
    k_ln    <<<512,                  256, 0, stream>>>(x, signal, gamma, beta, out);
}

// Round 5
// 39.588 us; speedup vs baseline: 3.3081x; 1.2146x over previous
//
#include <hip/hip_runtime.h>
#include <math.h>

#define SDIM 512
#define DDIM 256
#define NBATCH 4
#define SSQ (SDIM*SDIM)            // 262144
#define MED_K ((SSQ-1)/2)          // 131071
#define NBINS 4096
#define HMAX 48.0f                 // fixed histogram range [0, HMAX)
#define PADK 264                   // bf16 LDS row stride (256 + 8): breaks bank phase

// ---- workspace layout (bytes) ----
#define OFF_DISTS   0ull                               // 4 MB: float[4][512][512]
#define OFF_HIST    (4ull<<20)                         // 64 KB: uint[4][4096]
#define OFF_STATS   ((4ull<<20) + 65536ull)            // 128 B: per batch 4 doubles
#define OFF_SIGNAL  ((4ull<<20) + 65664ull)            // 4 KB: float[4][256]
#define OFF_ADJ     ((4ull<<20) + 69760ull)            // 128 KB: u64[4][512][8]
#define NZERO ((65536 + 128) / 4)                      // u32 words to zero (hist+stats)

typedef __attribute__((ext_vector_type(8))) short short8_t;
typedef __attribute__((ext_vector_type(4))) float f32x4_t;

__device__ __forceinline__ unsigned short f2bf(float f) {
    unsigned u = __float_as_uint(f);
    return (unsigned short)((u + 0x7FFFu + ((u >> 16) & 1u)) >> 16);   // RNE
}

// ---------------------------------------------------------------------------
// 0) zero hist+stats
__global__ __launch_bounds__(256) void k_zero(unsigned* __restrict__ z) {
    const int i = blockIdx.x * 256 + threadIdx.x;
    if (i < NZERO) z[i] = 0u;
}

// ---------------------------------------------------------------------------
// 1) pairwise distances via d^2 = |a|^2+|b|^2-2*Gram, Gram by bf16 MFMA.
//    64x64 tile / block, 4 waves; wave w computes rows [w*16,w*16+16) x 64.
//    Norms kept in f32 (from staging). Layout-error-proof: A/B frags use the
//    identical LDS pattern (Gram symmetry cancels any k-permutation error).
//    Fused: fixed-range LDS histogram, triu sum/sumsq, global max.
__global__ __launch_bounds__(256) void k_dist(const float* __restrict__ x,
                                              float* __restrict__ dists,
                                              double* __restrict__ stats,
                                              unsigned* __restrict__ ghist) {
    const int b  = blockIdx.z;
    const int i0 = blockIdx.y * 64, j0 = blockIdx.x * 64;
    __shared__ __align__(16) unsigned short Ab[64 * PADK];   // 33 KB
    __shared__ __align__(16) unsigned short Bb[64 * PADK];   // 33 KB
    __shared__ unsigned lh[NBINS];                           // 16 KB
    __shared__ float nA[64], nB[64];
    const int tid = threadIdx.x;
    const float* xb = x + (size_t)b * SDIM * DDIM;

    for (int t = tid; t < NBINS; t += 256) lh[t] = 0u;

    // ---- stage both tiles as bf16 + f32 row norms ----
    {
        const int r = tid >> 2, sub = tid & 3;
        const float* arow = xb + (size_t)(i0 + r) * DDIM + sub * 64;
        const float* brow = xb + (size_t)(j0 + r) * DDIM + sub * 64;
        float nap = 0.f, nbp = 0.f;
#pragma unroll
        for (int q = 0; q < 16; ++q) {
            float4 a4 = *(const float4*)(arow + q * 4);
            float4 b4 = *(const float4*)(brow + q * 4);
            nap += a4.x * a4.x + a4.y * a4.y + a4.z * a4.z + a4.w * a4.w;
            nbp += b4.x * b4.x + b4.y * b4.y + b4.z * b4.z + b4.w * b4.w;
            ushort4 ap = { f2bf(a4.x), f2bf(a4.y), f2bf(a4.z), f2bf(a4.w) };
            ushort4 bp = { f2bf(b4.x), f2bf(b4.y), f2bf(b4.z), f2bf(b4.w) };
            *(ushort4*)&Ab[r * PADK + sub * 64 + q * 4] = ap;
            *(ushort4*)&Bb[r * PADK + sub * 64 + q * 4] = bp;
        }
        nap += __shfl_xor(nap, 1); nap += __shfl_xor(nap, 2);
        nbp += __shfl_xor(nbp, 1); nbp += __shfl_xor(nbp, 2);
        if (sub == 0) { nA[r] = nap; nB[r] = nbp; }
    }
    __syncthreads();

    // ---- MFMA Gram: wave w -> rows w*16..+16, 4 col-tiles of 16 ----
    const int w = tid >> 6, l = tid & 63;
    const int lrow = l & 15, lkb = l >> 4;           // frag: row=l&15, k=(l>>4)*8+j
    f32x4_t ac0 = {0.f, 0.f, 0.f, 0.f}, ac1 = ac0, ac2 = ac0, ac3 = ac0;
    const unsigned short* Ap  = &Ab[(w * 16 + lrow) * PADK + lkb * 8];
    const unsigned short* Bp0 = &Bb[(0  + lrow) * PADK + lkb * 8];
    const unsigned short* Bp1 = &Bb[(16 + lrow) * PADK + lkb * 8];
    const unsigned short* Bp2 = &Bb[(32 + lrow) * PADK + lkb * 8];
    const unsigned short* Bp3 = &Bb[(48 + lrow) * PADK + lkb * 8];
#pragma unroll
    for (int ks = 0; ks < 8; ++ks) {
        short8_t af = *(const short8_t*)(Ap  + ks * 32);
        short8_t b0 = *(const short8_t*)(Bp0 + ks * 32);
        short8_t b1 = *(const short8_t*)(Bp1 + ks * 32);
        short8_t b2 = *(const short8_t*)(Bp2 + ks * 32);
        short8_t b3 = *(const short8_t*)(Bp3 + ks * 32);
        ac0 = __builtin_amdgcn_mfma_f32_16x16x32_bf16(af, b0, ac0, 0, 0, 0);
        ac1 = __builtin_amdgcn_mfma_f32_16x16x32_bf16(af, b1, ac1, 0, 0, 0);
        ac2 = __builtin_amdgcn_mfma_f32_16x16x32_bf16(af, b2, ac2, 0, 0, 0);
        ac3 = __builtin_amdgcn_mfma_f32_16x16x32_bf16(af, b3, ac3, 0, 0, 0);
    }

    // ---- epilogue: d = sqrt(ni+nj-2g), hist, triu stats, max, store ----
    float* db = dists + (size_t)b * SSQ;
    const float hscale = (float)NBINS / HMAX;
    const int orow = w * 16 + lkb * 4;               // C/D: col=l&15, row=(l>>4)*4+reg
    float bm = 0.f, fsum = 0.f, fsumsq = 0.f;
#pragma unroll
    for (int c = 0; c < 4; ++c) {
        const f32x4_t a = (c == 0) ? ac0 : (c == 1) ? ac1 : (c == 2) ? ac2 : ac3;
        const int jl = c * 16 + lrow;
        const float njv = nB[jl];
        const int gj = j0 + jl;
#pragma unroll
        for (int reg = 0; reg < 4; ++reg) {
            const int il = orow + reg;
            const int gi = i0 + il;
            float sq = fmaf(-2.0f, a[reg], nA[il] + njv);
            float d  = sq > 0.f ? sqrtf(sq) : 0.f;
            if (gi == gj) d = 0.f;
            bm = fmaxf(bm, d);
            db[(size_t)gi * SDIM + gj] = d;
            int bin = (int)(d * hscale);
            bin = bin > (NBINS - 1) ? (NBINS - 1) : bin;
            atomicAdd(&lh[bin], 1u);
            if (gj >= gi) { fsum += d; fsumsq += d * d; }
        }
    }
    // block reductions
    double s = (double)fsum, q = (double)fsumsq;
#pragma unroll
    for (int off = 32; off; off >>= 1) {
        bm = fmaxf(bm, __shfl_xor(bm, off));
        s += __shfl_xor(s, off);
        q += __shfl_xor(q, off);
    }
    __shared__ float wm[4];
    __shared__ double ws_[4], wq[4];
    if (l == 0) { wm[w] = bm; ws_[w] = s; wq[w] = q; }
    __syncthreads();
    if (tid == 0) {
        double* st = stats + (size_t)b * 4;
        float m = fmaxf(fmaxf(wm[0], wm[1]), fmaxf(wm[2], wm[3]));
        atomicMax((unsigned*)(st + 2), __float_as_uint(m));
        atomicAdd(&st[0], ws_[0] + ws_[1] + ws_[2] + ws_[3]);
        atomicAdd(&st[1], wq[0] + wq[1] + wq[2] + wq[3]);
    }
    unsigned* gh = ghist + (size_t)b * NBINS;
    for (int t = tid; t < NBINS; t += 256) {
        unsigned v = lh[t];
        if (v) atomicAdd(&gh[t], v);
    }
}

// ---------------------------------------------------------------------------
// 2) adjacency: inline median scan, ballot bitmask build + edge count.
__global__ __launch_bounds__(256) void k_adj(const float* __restrict__ dists,
                                             const unsigned* __restrict__ ghist,
                                             unsigned long long* __restrict__ adj,
                                             double* __restrict__ stats) {
    const int b = blockIdx.y, tid = threadIdx.x;
    const unsigned* h = ghist + (size_t)b * NBINS;
    unsigned lcnt[16];
    unsigned local = 0;
#pragma unroll
    for (int t = 0; t < 16; ++t) { lcnt[t] = h[tid * 16 + t]; local += lcnt[t]; }
    __shared__ unsigned psum[256];
    __shared__ float sthr;
    psum[tid] = local;
    __syncthreads();
    for (int off = 1; off < 256; off <<= 1) {
        unsigned v = 0;
        if (tid >= off) v = psum[tid - off];
        __syncthreads();
        psum[tid] += v;
        __syncthreads();
    }
    const unsigned excl = psum[tid] - local;
    if (MED_K >= excl && MED_K < excl + local) {
        unsigned run = excl;
        int bucket = tid * 16;
        for (int t = 0; t < 16; ++t) {
            if (MED_K < run + lcnt[t]) { bucket = tid * 16 + t; break; }
            run += lcnt[t];
        }
        sthr = ((float)bucket + 0.5f) * (HMAX / (float)NBINS);
    }
    __syncthreads();
    const float thr = sthr;

    const int w = tid >> 6, lane = tid & 63;
    const int i = blockIdx.x * 4 + w;
    const float* row = dists + (size_t)b * SSQ + (size_t)i * SDIM;
    int conn = 0;
    unsigned long long words[8];
#pragma unroll
    for (int c = 0; c < 8; ++c) {
        int j = c * 64 + lane;
        float d = row[j];
        bool pred = (d < thr) && (j != i);
        words[c] = __ballot(pred ? 1 : 0);
        conn += pred ? 1 : 0;
    }
    if (lane == 0) {
#pragma unroll
        for (int c = 0; c < 8; ++c) adj[((size_t)b * SDIM + i) * 8 + c] = words[c];
    }
#pragma unroll
    for (int off = 32; off; off >>= 1) conn += __shfl_xor(conn, off);
    __shared__ int sh_c[4];
    if (lane == 0) sh_c[w] = conn;
    __syncthreads();
    if (tid == 0) {
        unsigned C0 = (unsigned)(sh_c[0] + sh_c[1] + sh_c[2] + sh_c[3]);
        atomicAdd(((unsigned*)(stats + (size_t)b * 4 + 2)) + 1, C0);
    }
}

// ---------------------------------------------------------------------------
// 3) connected components by ballot-BFS + topo-feature matvec (signal).
__global__ __launch_bounds__(512) void k_ccsig(const uint4* __restrict__ adj,
                                               const double* __restrict__ stats,
                                               const float* __restrict__ W,
                                               const float* __restrict__ bias,
                                               float* __restrict__ signal) {
    const int b = blockIdx.x;
    __shared__ uint4 am[SDIM][4];
    __shared__ unsigned frontW[16], reachW[16];
    __shared__ int s_next, s_ncomp, s_any;
    const int tid = threadIdx.x;
    const uint4* ab = adj + (size_t)b * SDIM * 4;
    for (int t = tid; t < SDIM * 4; t += 512) ((uint4*)am)[t] = ab[t];
    if (tid < 16) { frontW[tid] = 0u; reachW[tid] = 0u; }
    if (tid == 0) s_ncomp = 0;
    __syncthreads();

    bool myReached = false;
    for (int comp = 0; comp < SDIM; ++comp) {
        if (tid == 0) {
            int s = -1;
            for (int w = 0; w < 16 && s < 0; ++w) {
                unsigned m = ~reachW[w];
                if (m) s = w * 32 + __ffs(m) - 1;
            }
            s_next = s;
            if (s >= 0) s_ncomp++;
        }
        __syncthreads();
        const int s = s_next;
        if (s < 0) break;
        if (tid < 16) {
            unsigned f = (tid == (s >> 5)) ? (1u << (s & 31)) : 0u;
            frontW[tid] = f;
            reachW[tid] |= f;
        }
        if (tid == s) myReached = true;
        __syncthreads();

        for (int it = 0; it < SDIM; ++it) {
            const uint4 f0 = *(const uint4*)&frontW[0];
            const uint4 f1 = *(const uint4*)&frontW[4];
            const uint4 f2 = *(const uint4*)&frontW[8];
            const uint4 f3 = *(const uint4*)&frontW[12];
            const uint4 r0 = am[tid][0], r1 = am[tid][1];
            const uint4 r2 = am[tid][2], r3 = am[tid][3];
            const unsigned inter =
                (r0.x & f0.x) | (r0.y & f0.y) | (r0.z & f0.z) | (r0.w & f0.w) |
                (r1.x & f1.x) | (r1.y & f1.y) | (r1.z & f1.z) | (r1.w & f1.w) |
                (r2.x & f2.x) | (r2.y & f2.y) | (r2.z & f2.z) | (r2.w & f2.w) |
                (r3.x & f3.x) | (r3.y & f3.y) | (r3.z & f3.z) | (r3.w & f3.w);
            const bool act = (inter != 0u) && !myReached;
            const unsigned long long bal = __ballot(act ? 1 : 0);
            __syncthreads();
            if ((tid & 63) == 0) {
                const int wv = tid >> 6;
                frontW[wv * 2]     = (unsigned)bal;
                frontW[wv * 2 + 1] = (unsigned)(bal >> 32);
            }
            if (tid == 0) s_any = 0;
            __syncthreads();
            if (act) myReached = true;
            if (tid < 16) {
                unsigned nf = frontW[tid];
                reachW[tid] |= nf;
                if (nf) atomicOr(&s_any, 1);
            }
            __syncthreads();
            if (!s_any) break;
        }
    }
    __syncthreads();

    if (tid < DDIM) {
        const double* st = stats + (size_t)b * 4;
        const double sum = st[0], sumsq = st[1];
        const unsigned maxbits = ((const unsigned*)&st[2])[0];
        const unsigned conn    = ((const unsigned*)&st[2])[1];
        const double cntf = (double)(SDIM * (SDIM + 1) / 2);
        const double mean = sum / cntf;
        double var = (sumsq - sum * sum / cntf) / (cntf - 1.0);
        var = var > 0.0 ? var : 0.0;
        const float t0 = (float)((double)conn / (double)(SDIM * (SDIM - 1)));
        const float t1 = (float)s_ncomp / (float)SDIM;
        const float t2 = (float)((double)conn / (double)(SDIM * SDIM));
        const float t3 = (float)mean;
        const float t4 = (float)sqrt(var);
        const float t6 = __uint_as_float(maxbits);
        const float* w = W + tid * 8;
        signal[b * DDIM + tid] = bias[tid] + t0 * w[0] + t1 * w[1] + t2 * w[2]
                               + t3 * w[3] + t4 * w[4] + t6 * w[6];
    }
}

// ---------------------------------------------------------------------------
// 4) residual + LayerNorm, wave per row
__global__ __launch_bounds__(256) void k_ln(const float* __restrict__ x,
                                            const float* __restrict__ signal,
                                            const float* __restrict__ gamma,
                                            const float* __restrict__ beta,
                                            float* __restrict__ out) {
    const int tid = threadIdx.x;
    const int w = tid >> 6, lane = tid & 63;
    const int row = blockIdx.x * 4 + w;
    const int b = row >> 9;
    const float4 xv = *(const float4*)(x + (size_t)row * DDIM + lane * 4);
    const float4 sg = *(const float4*)(signal + (size_t)b * DDIM + lane * 4);
    float h0 = xv.x + sg.x, h1 = xv.y + sg.y, h2 = xv.z + sg.z, h3 = xv.w + sg.w;
    float s = h0 + h1 + h2 + h3;
#pragma unroll
    for (int off = 32; off; off >>= 1) s += __shfl_xor(s, off);
    const float mu = s * (1.0f / 256.0f);
    const float d0 = h0 - mu, d1 = h1 - mu, d2 = h2 - mu, d3 = h3 - mu;
    float q = d0 * d0 + d1 * d1 + d2 * d2 + d3 * d3;
#pragma unroll
    for (int off = 32; off; off >>= 1) q += __shfl_xor(q, off);
    const float var = q * (1.0f / 256.0f);
    const float r = 1.0f / sqrtf(var + 1e-5f);
    const float4 g  = *(const float4*)(gamma + lane * 4);
    const float4 be = *(const float4*)(beta + lane * 4);
    float4 o;
    o.x = d0 * r * g.x + be.x;
    o.y = d1 * r * g.y + be.y;
    o.z = d2 * r * g.z + be.z;
    o.w = d3 * r * g.w + be.w;
    *(float4*)(out + (size_t)row * DDIM + lane * 4) = o;
}

// ---------------------------------------------------------------------------
extern "C" void kernel_launch(void* const* d_in, const int* in_sizes, int n_in,
                              void* d_out, int out_size, void* d_ws, size_t ws_size,
                              hipStream_t stream) {
    (void)in_sizes; (void)n_in; (void)out_size; (void)ws_size;
    const float* x     = (const float*)d_in[0];
    const float* W     = (const float*)d_in[1];
    const float* bias  = (const float*)d_in[2];
    const float* gamma = (const float*)d_in[3];
    const float* beta  = (const float*)d_in[4];
    float* out = (float*)d_out;

    char* ws = (char*)d_ws;
    float*    dists  = (float*)(ws + OFF_DISTS);
    unsigned* ghist  = (unsigned*)(ws + OFF_HIST);
    double*   stats  = (double*)(ws + OFF_STATS);
    float*    signal = (float*)(ws + OFF_SIGNAL);
    unsigned long long* adj = (unsigned long long*)(ws + OFF_ADJ);

    k_zero  <<<(NZERO + 255) / 256,  256, 0, stream>>>((unsigned*)(ws + OFF_HIST));
    k_dist  <<<dim3(8, 8, NBATCH),   256, 0, stream>>>(x, dists, stats, ghist);
    k_adj   <<<dim3(128, NBATCH),    256, 0, stream>>>(dists, ghist, adj, stats);
    k_ccsig <<<NBATCH,               512, 0, stream>>>((const uint4*)adj, stats, W, bias, signal);
    k_ln    <<<512,                  256, 0, stream>>>(x, signal, gamma, beta, out);
}